// Round 6
// baseline (3402.090 us; speedup 1.0000x reference)
//
#include <hip/hip_runtime.h>

#define EPSF    1e-10f
#define MAXENT  6.93147180559945286f   // ln(1024)
#define SCALEF  0.37796447300922720f   // 1/sqrt(7)

// ---------------- helpers ----------------
__device__ __forceinline__ float wave_sum(float v) {
#pragma unroll
  for (int off = 32; off > 0; off >>= 1) v += __shfl_xor(v, off);
  return v;
}
__device__ __forceinline__ void fma4(float a, float4 b, float4& c) {
  c.x = fmaf(a, b.x, c.x); c.y = fmaf(a, b.y, c.y);
  c.z = fmaf(a, b.z, c.z); c.w = fmaf(a, b.w, c.w);
}
__device__ __forceinline__ float exp4sum(float4 s) {
  return __expf(s.x) + __expf(s.y) + __expf(s.z) + __expf(s.w);
}
// P0 = (E1*exp(s1) + E2*exp(s2) + EPS)^10, E_h = 0.5/L_h (no-max softmax; |s|<~12 so safe)
__device__ __forceinline__ float p0e(float s1, float s2, float E1, float E2) {
  float p = fmaf(E1, __expf(s1), fmaf(E2, __expf(s2), EPSF));
  float p2 = p * p, p4 = p2 * p2, p5 = p4 * p;
  return p5 * p5;
}

// ---------------- kernel 0: QKV projection (d-major, Q pre-scaled) + R/C init ----------------
__global__ __launch_bounds__(256) void qkv_kernel(
    const float* __restrict__ x,
    const float* __restrict__ Wq, const float* __restrict__ bq,
    const float* __restrict__ Wk, const float* __restrict__ bk,
    const float* __restrict__ Wv, const float* __restrict__ bv,
    float* __restrict__ Qt, float* __restrict__ Kt, float* __restrict__ Vt,
    float* __restrict__ R, float* __restrict__ C) {
  int row = blockIdx.x * 256 + threadIdx.x;     // 65536 rows
  int b = row >> 10, i = row & 1023;
  float xv[14];
#pragma unroll
  for (int k = 0; k < 14; k++) xv[k] = x[row * 14 + k];
#pragma unroll
  for (int d = 0; d < 14; d++) {
    float q = bq[d], kk = bk[d], vv = bv[d];
#pragma unroll
    for (int k = 0; k < 14; k++) {
      q  = fmaf(xv[k], Wq[d * 14 + k], q);
      kk = fmaf(xv[k], Wk[d * 14 + k], kk);
      vv = fmaf(xv[k], Wv[d * 14 + k], vv);
    }
    int o = b * 14336 + d * 1024 + i;
    Qt[o] = q * SCALEF;
    Kt[o] = kk; Vt[o] = vv;
  }
  R[row] = 1.0f;
  C[row] = 1.0f;
}

// ---------------- kernel 1: fused attention + entropy/certainty + E1/E2 ----------------
__global__ __launch_bounds__(512) void attn_kernel(
    const float* __restrict__ Qt, const float* __restrict__ Kt, const float* __restrict__ Vt,
    const float* __restrict__ cert_in,
    float* __restrict__ E1o, float* __restrict__ E2o,
    float* __restrict__ attn_o, float* __restrict__ cert_out) {
  __shared__ float4 Kl[3584];                   // 56 KB
  int b = blockIdx.x >> 6;
  int rg = blockIdx.x & 63;
  int tid = threadIdx.x;
  const float4* Ktb = (const float4*)(Kt + b * 14336);
  for (int idx = tid; idx < 3584; idx += 512) Kl[idx] = Ktb[idx];
  __syncthreads();

  int wave = tid >> 6, lane = tid & 63;
  int i0 = rg * 16 + wave * 2;
  float q0[14], q1[14];
#pragma unroll
  for (int d = 0; d < 14; d++) {
    q0[d] = Qt[b * 14336 + d * 1024 + i0];
    q1[d] = Qt[b * 14336 + d * 1024 + i0 + 1];
  }

  float L10 = 0.f, L20 = 0.f, L11 = 0.f, L21 = 0.f;
#pragma unroll
  for (int t = 0; t < 4; t++) {
    int g = t * 64 + lane;
    float4 kv[7];
#pragma unroll
    for (int d = 0; d < 7; d++) kv[d] = Kl[d * 256 + g];
    float4 sa = {0,0,0,0}, sb = {0,0,0,0};
#pragma unroll
    for (int d = 0; d < 7; d++) { fma4(q0[d], kv[d], sa); fma4(q1[d], kv[d], sb); }
    L10 += exp4sum(sa); L11 += exp4sum(sb);
#pragma unroll
    for (int d = 0; d < 7; d++) kv[d] = Kl[(d + 7) * 256 + g];
    sa = make_float4(0,0,0,0); sb = make_float4(0,0,0,0);
#pragma unroll
    for (int d = 0; d < 7; d++) { fma4(q0[d + 7], kv[d], sa); fma4(q1[d + 7], kv[d], sb); }
    L20 += exp4sum(sa); L21 += exp4sum(sb);
  }
  L10 = wave_sum(L10); L20 = wave_sum(L20);
  L11 = wave_sum(L11); L21 = wave_sum(L21);
  float i10 = 1.0f / L10, i20 = 1.0f / L20, i11 = 1.0f / L11, i21 = 1.0f / L21;

  float acc0[14], acc1[14];
#pragma unroll
  for (int d = 0; d < 14; d++) { acc0[d] = 0.f; acc1[d] = 0.f; }
  float ent0 = 0.f, ent1 = 0.f;
  const float4* Vtb = (const float4*)(Vt + b * 14336);
#pragma unroll
  for (int t = 0; t < 4; t++) {
    int g = t * 64 + lane;
    float4 kv[7];
#pragma unroll
    for (int d = 0; d < 7; d++) kv[d] = Kl[d * 256 + g];
    float4 sa = {0,0,0,0}, sb = {0,0,0,0};
#pragma unroll
    for (int d = 0; d < 7; d++) { fma4(q0[d], kv[d], sa); fma4(q1[d], kv[d], sb); }
    float4 e10 = make_float4(__expf(sa.x), __expf(sa.y), __expf(sa.z), __expf(sa.w));
    float4 e11 = make_float4(__expf(sb.x), __expf(sb.y), __expf(sb.z), __expf(sb.w));
#pragma unroll
    for (int d = 0; d < 7; d++) kv[d] = Kl[(d + 7) * 256 + g];
    sa = make_float4(0,0,0,0); sb = make_float4(0,0,0,0);
#pragma unroll
    for (int d = 0; d < 7; d++) { fma4(q0[d + 7], kv[d], sa); fma4(q1[d + 7], kv[d], sb); }
    float4 e20 = make_float4(__expf(sa.x), __expf(sa.y), __expf(sa.z), __expf(sa.w));
    float4 e21 = make_float4(__expf(sb.x), __expf(sb.y), __expf(sb.z), __expf(sb.w));
#pragma unroll
    for (int d = 0; d < 7; d++) {
      float4 vv = Vtb[d * 256 + g];
      acc0[d] += e10.x * vv.x + e10.y * vv.y + e10.z * vv.z + e10.w * vv.w;
      acc1[d] += e11.x * vv.x + e11.y * vv.y + e11.z * vv.z + e11.w * vv.w;
    }
#pragma unroll
    for (int d = 7; d < 14; d++) {
      float4 vv = Vtb[d * 256 + g];
      acc0[d] += e20.x * vv.x + e20.y * vv.y + e20.z * vv.z + e20.w * vv.w;
      acc1[d] += e21.x * vv.x + e21.y * vv.y + e21.z * vv.z + e21.w * vv.w;
    }
    float a;
    a = 0.5f * (e10.x * i10 + e20.x * i20); ent0 -= a * __logf(a + EPSF);
    a = 0.5f * (e10.y * i10 + e20.y * i20); ent0 -= a * __logf(a + EPSF);
    a = 0.5f * (e10.z * i10 + e20.z * i20); ent0 -= a * __logf(a + EPSF);
    a = 0.5f * (e10.w * i10 + e20.w * i20); ent0 -= a * __logf(a + EPSF);
    a = 0.5f * (e11.x * i11 + e21.x * i21); ent1 -= a * __logf(a + EPSF);
    a = 0.5f * (e11.y * i11 + e21.y * i21); ent1 -= a * __logf(a + EPSF);
    a = 0.5f * (e11.z * i11 + e21.z * i21); ent1 -= a * __logf(a + EPSF);
    a = 0.5f * (e11.w * i11 + e21.w * i21); ent1 -= a * __logf(a + EPSF);
  }
  ent0 = wave_sum(ent0); ent1 = wave_sum(ent1);
#pragma unroll
  for (int d = 0; d < 14; d++) { acc0[d] = wave_sum(acc0[d]); acc1[d] = wave_sum(acc1[d]); }

  if (lane == 0) {
    int row0 = b * 1024 + i0;
    E1o[row0] = 0.5f * i10;  E2o[row0] = 0.5f * i20;
    E1o[row0 + 1] = 0.5f * i11; E2o[row0 + 1] = 0.5f * i21;
#pragma unroll
    for (int d = 0; d < 14; d++) {
      attn_o[row0 * 14 + d] = acc0[d] * (d < 7 ? i10 : i20);
      attn_o[(row0 + 1) * 14 + d] = acc1[d] * (d < 7 ? i11 : i21);
    }
    cert_out[row0] = fmaxf(cert_in[row0], 1.0f / (1.0f + __expf(ent0 - MAXENT)));
    cert_out[row0 + 1] = fmaxf(cert_in[row0 + 1], 1.0f / (1.0f + __expf(ent1 - MAXENT)));
  }
}

// ---------------- kernel 2: output projection ----------------
__global__ __launch_bounds__(256) void proj_kernel(
    const float* __restrict__ attn_o, const float* __restrict__ Wo,
    const float* __restrict__ bo, float* __restrict__ out) {
  int idx = blockIdx.x * 256 + threadIdx.x;     // 917504 = 65536*14
  if (idx >= 917504) return;
  int row = idx / 14, d = idx - row * 14;
  float s = bo[d];
  const float* ar = attn_o + row * 14;
  const float* wr = Wo + d * 14;
#pragma unroll
  for (int k = 0; k < 14; k++) s = fmaf(ar[k], wr[k], s);
  out[idx] = s;
}

// ================= FAST PATH: grouped materialized P0 =================

// precompute P0 for G batches starting at b0; grid = G*32 blocks, 32 rows/block
__global__ __launch_bounds__(512) void p0pre_kernel(
    const float* __restrict__ Qt, const float* __restrict__ Kt,
    const float* __restrict__ E1, const float* __restrict__ E2,
    float* __restrict__ P0, int b0) {
  __shared__ float4 Kl[3584];
  int gb = blockIdx.x >> 5, blk = blockIdx.x & 31;
  int b = b0 + gb;
  int tid = threadIdx.x;
  const float4* Ktb = (const float4*)(Kt + b * 14336);
  for (int idx = tid; idx < 3584; idx += 512) Kl[idx] = Ktb[idx];
  __syncthreads();

  int wave = tid >> 6, lane = tid & 63;
  int i0 = blk * 32 + wave * 4;
  float q[4][14], e1r[4], e2r[4];
#pragma unroll
  for (int rr = 0; rr < 4; rr++) {
#pragma unroll
    for (int d = 0; d < 14; d++) q[rr][d] = Qt[b * 14336 + d * 1024 + i0 + rr];
    e1r[rr] = E1[b * 1024 + i0 + rr];
    e2r[rr] = E2[b * 1024 + i0 + rr];
  }
  float4* P0f4 = (float4*)P0;
#pragma unroll
  for (int t = 0; t < 4; t++) {
    int g = t * 64 + lane;
    float4 kv[14];
#pragma unroll
    for (int d = 0; d < 14; d++) kv[d] = Kl[d * 256 + g];
#pragma unroll
    for (int rr = 0; rr < 4; rr++) {
      float4 s1 = {0,0,0,0}, s2 = {0,0,0,0};
#pragma unroll
      for (int d = 0; d < 7; d++)  fma4(q[rr][d], kv[d], s1);
#pragma unroll
      for (int d = 7; d < 14; d++) fma4(q[rr][d], kv[d], s2);
      float4 pv;
      pv.x = p0e(s1.x, s2.x, e1r[rr], e2r[rr]);
      pv.y = p0e(s1.y, s2.y, e1r[rr], e2r[rr]);
      pv.z = p0e(s1.z, s2.z, e1r[rr], e2r[rr]);
      pv.w = p0e(s1.w, s2.w, e1r[rr], e2r[rr]);
      P0f4[(size_t)(gb * 1024 + i0 + rr) * 256 + g] = pv;
    }
  }
}

// fused Sinkhorn iteration v2: 256-thr blocks, S slices, one row-chain per wave step.
// grid = G << logS; rows/block = 1024>>logS; rows/wave = (1024>>logS)/4
__global__ __launch_bounds__(256) void sink_fused(
    const float* __restrict__ P0, const float* __restrict__ Cg,
    float* __restrict__ R, float* __restrict__ vpart,
    int b0, int G, int logS) {
  __shared__ float vbuf[1024];
  int tid = threadIdx.x;
  for (int idx = tid; idx < 1024; idx += 256) vbuf[idx] = 0.f;
  __syncthreads();
  int S = 1 << logS;
  int gb = blockIdx.x >> logS, slice = blockIdx.x & (S - 1);
  int b = b0 + gb;
  int wave = tid >> 6, lane = tid & 63;
  int rpb = 1024 >> logS;                       // rows per block
  int rpw = rpb >> 2;                           // rows per wave (4 waves)
  int i0 = slice * rpb + wave * rpw;
  int rbase = b * 1024 + i0;
  const float4* Cb = (const float4*)(Cg + b * 1024);
  float4 c0 = Cb[lane], c1 = Cb[64 + lane], c2 = Cb[128 + lane], c3 = Cb[192 + lane];
  float4 v0 = {0,0,0,0}, v1 = {0,0,0,0}, v2 = {0,0,0,0}, v3 = {0,0,0,0};
  const float4* P0f4 = (const float4*)P0;

  for (int r = 0; r < rpw; r++) {
    const float4* Prow = P0f4 + (size_t)(gb * 1024 + i0 + r) * 256;
    float4 p0 = Prow[lane], p1 = Prow[64 + lane], p2 = Prow[128 + lane], p3 = Prow[192 + lane];
    float rv = R[rbase + r];                    // broadcast load, independent of dot
    float u = p0.x * c0.x;
    u = fmaf(p0.y, c0.y, u); u = fmaf(p0.z, c0.z, u); u = fmaf(p0.w, c0.w, u);
    u = fmaf(p1.x, c1.x, u); u = fmaf(p1.y, c1.y, u); u = fmaf(p1.z, c1.z, u); u = fmaf(p1.w, c1.w, u);
    u = fmaf(p2.x, c2.x, u); u = fmaf(p2.y, c2.y, u); u = fmaf(p2.z, c2.z, u); u = fmaf(p2.w, c2.w, u);
    u = fmaf(p3.x, c3.x, u); u = fmaf(p3.y, c3.y, u); u = fmaf(p3.z, c3.z, u); u = fmaf(p3.w, c3.w, u);
    u = wave_sum(u);
    rv = fminf(rv / fmaf(rv, u, EPSF), 1e37f);
    if (lane == 0) R[rbase + r] = rv;
    fma4(rv, p0, v0); fma4(rv, p1, v1); fma4(rv, p2, v2); fma4(rv, p3, v3);
  }
  // merge 4 waves' column partials in LDS
  atomicAdd(&vbuf[4 * lane + 0], v0.x); atomicAdd(&vbuf[4 * lane + 1], v0.y);
  atomicAdd(&vbuf[4 * lane + 2], v0.z); atomicAdd(&vbuf[4 * lane + 3], v0.w);
  atomicAdd(&vbuf[256 + 4 * lane + 0], v1.x); atomicAdd(&vbuf[256 + 4 * lane + 1], v1.y);
  atomicAdd(&vbuf[256 + 4 * lane + 2], v1.z); atomicAdd(&vbuf[256 + 4 * lane + 3], v1.w);
  atomicAdd(&vbuf[512 + 4 * lane + 0], v2.x); atomicAdd(&vbuf[512 + 4 * lane + 1], v2.y);
  atomicAdd(&vbuf[512 + 4 * lane + 2], v2.z); atomicAdd(&vbuf[512 + 4 * lane + 3], v2.w);
  atomicAdd(&vbuf[768 + 4 * lane + 0], v3.x); atomicAdd(&vbuf[768 + 4 * lane + 1], v3.y);
  atomicAdd(&vbuf[768 + 4 * lane + 2], v3.z); atomicAdd(&vbuf[768 + 4 * lane + 3], v3.w);
  __syncthreads();
  float* vp = vpart + (size_t)(slice * G + gb) * 1024;
  for (int idx = tid; idx < 1024; idx += 256) vp[idx] = vbuf[idx];
}

// C update: v = sum of S slice partials, then C = C/(C*v+eps)
__global__ __launch_bounds__(256) void cupdate_kernel(
    float* __restrict__ C, const float* __restrict__ vpart, int b0, int G, int S) {
  int idx = blockIdx.x * 256 + threadIdx.x;     // < G*1024
  int gb = idx >> 10, j = idx & 1023;
  float v = 0.f;
  for (int s = 0; s < S; s++) v += vpart[(size_t)(s * G + gb) * 1024 + j];
  int o = (b0 + gb) * 1024 + j;
  float cv = C[o];
  C[o] = fminf(cv / fmaf(cv, v, EPSF), 1e37f);
}

// argmax over stored P0 * C + permutation gather; grid = G*128
__global__ __launch_bounds__(512) void argmaxP_kernel(
    const float* __restrict__ P0, const float* __restrict__ Cg,
    const int* __restrict__ perm, float* __restrict__ perm_out, int b0) {
  int gb = blockIdx.x >> 7, rg = blockIdx.x & 127;
  int b = b0 + gb;
  int tid = threadIdx.x;
  int wave = tid >> 6, lane = tid & 63;
  int i = rg * 8 + wave;
  const float4* Cb = (const float4*)(Cg + b * 1024);
  const float4* Prow = (const float4*)P0 + (size_t)(gb * 1024 + i) * 256;

  float best = -1.0f;
  int bj = 0;
#pragma unroll
  for (int t = 0; t < 4; t++) {
    int g = t * 64 + lane;
    float4 pv = Prow[g], cv = Cb[g];
    float val;
    val = pv.x * cv.x; if (val > best) { best = val; bj = 4 * g + 0; }
    val = pv.y * cv.y; if (val > best) { best = val; bj = 4 * g + 1; }
    val = pv.z * cv.z; if (val > best) { best = val; bj = 4 * g + 2; }
    val = pv.w * cv.w; if (val > best) { best = val; bj = 4 * g + 3; }
  }
#pragma unroll
  for (int off = 32; off > 0; off >>= 1) {
    float ob = __shfl_xor(best, off);
    int oj = __shfl_xor(bj, off);
    if (ob > best || (ob == best && oj < bj)) { best = ob; bj = oj; }
  }
  if (lane == 0) perm_out[b * 1024 + i] = (float)perm[b * 1024 + bj];
}

// ================= FALLBACK PATH (round-3, recompute) =================

__global__ __launch_bounds__(512) void sinkA_kernel(
    const float* __restrict__ Qt, const float* __restrict__ Kt,
    const float* __restrict__ E1, const float* __restrict__ E2,
    const float* __restrict__ C, float* __restrict__ R) {
  __shared__ float4 Kl[3584];
  int b = blockIdx.x >> 5, blk = blockIdx.x & 31;
  int tid = threadIdx.x;
  const float4* Ktb = (const float4*)(Kt + b * 14336);
  for (int idx = tid; idx < 3584; idx += 512) Kl[idx] = Ktb[idx];
  __syncthreads();
  int wave = tid >> 6, lane = tid & 63;
  int i0 = blk * 32 + wave * 4;
  float q[4][14], e1r[4], e2r[4], u[4];
#pragma unroll
  for (int rr = 0; rr < 4; rr++) {
#pragma unroll
    for (int d = 0; d < 14; d++) q[rr][d] = Qt[b * 14336 + d * 1024 + i0 + rr];
    e1r[rr] = E1[b * 1024 + i0 + rr];
    e2r[rr] = E2[b * 1024 + i0 + rr];
    u[rr] = 0.f;
  }
  const float4* Cb = (const float4*)(C + b * 1024);
#pragma unroll
  for (int t = 0; t < 4; t++) {
    int g = t * 64 + lane;
    float4 kv[14];
#pragma unroll
    for (int d = 0; d < 14; d++) kv[d] = Kl[d * 256 + g];
    float4 cv = Cb[g];
#pragma unroll
    for (int rr = 0; rr < 4; rr++) {
      float4 s1 = {0,0,0,0}, s2 = {0,0,0,0};
#pragma unroll
      for (int d = 0; d < 7; d++)  fma4(q[rr][d], kv[d], s1);
#pragma unroll
      for (int d = 7; d < 14; d++) fma4(q[rr][d], kv[d], s2);
      u[rr] += p0e(s1.x, s2.x, e1r[rr], e2r[rr]) * cv.x;
      u[rr] += p0e(s1.y, s2.y, e1r[rr], e2r[rr]) * cv.y;
      u[rr] += p0e(s1.z, s2.z, e1r[rr], e2r[rr]) * cv.z;
      u[rr] += p0e(s1.w, s2.w, e1r[rr], e2r[rr]) * cv.w;
    }
  }
#pragma unroll
  for (int rr = 0; rr < 4; rr++) u[rr] = wave_sum(u[rr]);
  if (lane == 0) {
#pragma unroll
    for (int rr = 0; rr < 4; rr++) {
      int o = b * 1024 + i0 + rr;
      float rv = R[o];
      R[o] = fminf(rv / fmaf(rv, u[rr], EPSF), 1e37f);
    }
  }
}

__global__ __launch_bounds__(512) void sinkB_kernel(
    const float* __restrict__ Qt, const float* __restrict__ Kt,
    const float* __restrict__ E1, const float* __restrict__ E2,
    const float* __restrict__ R, float* __restrict__ C) {
  __shared__ float4 Ql[3584];
  int b = blockIdx.x >> 5, blk = blockIdx.x & 31;
  int tid = threadIdx.x;
  const float4* Qtb = (const float4*)(Qt + b * 14336);
  for (int idx = tid; idx < 3584; idx += 512) Ql[idx] = Qtb[idx];
  __syncthreads();
  int wave = tid >> 6, lane = tid & 63;
  int j0 = blk * 32 + wave * 4;
  float kk[4][14], v[4];
#pragma unroll
  for (int rr = 0; rr < 4; rr++) {
#pragma unroll
    for (int d = 0; d < 14; d++) kk[rr][d] = Kt[b * 14336 + d * 1024 + j0 + rr];
    v[rr] = 0.f;
  }
  const float4* E1b = (const float4*)(E1 + b * 1024);
  const float4* E2b = (const float4*)(E2 + b * 1024);
  const float4* Rb  = (const float4*)(R + b * 1024);
#pragma unroll
  for (int t = 0; t < 4; t++) {
    int g = t * 64 + lane;
    float4 qv[14];
#pragma unroll
    for (int d = 0; d < 14; d++) qv[d] = Ql[d * 256 + g];
    float4 e1v = E1b[g], e2v = E2b[g], rv = Rb[g];
#pragma unroll
    for (int rr = 0; rr < 4; rr++) {
      float4 s1 = {0,0,0,0}, s2 = {0,0,0,0};
#pragma unroll
      for (int d = 0; d < 7; d++)  fma4(kk[rr][d], qv[d], s1);
#pragma unroll
      for (int d = 7; d < 14; d++) fma4(kk[rr][d], qv[d], s2);
      v[rr] += p0e(s1.x, s2.x, e1v.x, e2v.x) * rv.x;
      v[rr] += p0e(s1.y, s2.y, e1v.y, e2v.y) * rv.y;
      v[rr] += p0e(s1.z, s2.z, e1v.z, e2v.z) * rv.z;
      v[rr] += p0e(s1.w, s2.w, e1v.w, e2v.w) * rv.w;
    }
  }
#pragma unroll
  for (int rr = 0; rr < 4; rr++) v[rr] = wave_sum(v[rr]);
  if (lane == 0) {
#pragma unroll
    for (int rr = 0; rr < 4; rr++) {
      int o = b * 1024 + j0 + rr;
      float cv = C[o];
      C[o] = fminf(cv / fmaf(cv, v[rr], EPSF), 1e37f);
    }
  }
}

__global__ __launch_bounds__(512) void argmax_kernel(
    const float* __restrict__ Qt, const float* __restrict__ Kt,
    const float* __restrict__ E1, const float* __restrict__ E2,
    const float* __restrict__ C, const int* __restrict__ perm,
    float* __restrict__ perm_out) {
  __shared__ float4 Kl[3584];
  int b = blockIdx.x >> 7, rg = blockIdx.x & 127;
  int tid = threadIdx.x;
  const float4* Ktb = (const float4*)(Kt + b * 14336);
  for (int idx = tid; idx < 3584; idx += 512) Kl[idx] = Ktb[idx];
  __syncthreads();
  int wave = tid >> 6, lane = tid & 63;
  int i = rg * 8 + wave;
  int row = b * 1024 + i;
  float q[14];
#pragma unroll
  for (int d = 0; d < 14; d++) q[d] = Qt[b * 14336 + d * 1024 + i];
  float e1r = E1[row], e2r = E2[row];
  const float4* Cb = (const float4*)(C + b * 1024);
  float best = -1.0f;
  int bj = 0;
#pragma unroll
  for (int t = 0; t < 4; t++) {
    int g = t * 64 + lane;
    float4 kv[14];
#pragma unroll
    for (int d = 0; d < 14; d++) kv[d] = Kl[d * 256 + g];
    float4 cv = Cb[g];
    float4 s1 = {0,0,0,0}, s2 = {0,0,0,0};
#pragma unroll
    for (int d = 0; d < 7; d++)  fma4(q[d], kv[d], s1);
#pragma unroll
    for (int d = 7; d < 14; d++) fma4(q[d], kv[d], s2);
    float val;
    val = p0e(s1.x, s2.x, e1r, e2r) * cv.x; if (val > best) { best = val; bj = 4 * g + 0; }
    val = p0e(s1.y, s2.y, e1r, e2r) * cv.y; if (val > best) { best = val; bj = 4 * g + 1; }
    val = p0e(s1.z, s2.z, e1r, e2r) * cv.z; if (val > best) { best = val; bj = 4 * g + 2; }
    val = p0e(s1.w, s2.w, e1r, e2r) * cv.w; if (val > best) { best = val; bj = 4 * g + 3; }
  }
#pragma unroll
  for (int off = 32; off > 0; off >>= 1) {
    float ob = __shfl_xor(best, off);
    int oj = __shfl_xor(bj, off);
    if (ob > best || (ob == best && oj < bj)) { best = ob; bj = oj; }
  }
  if (lane == 0) perm_out[row] = (float)perm[b * 1024 + bj];
}

// ---------------- launch ----------------
extern "C" void kernel_launch(void* const* d_in, const int* in_sizes, int n_in,
                              void* d_out, int out_size, void* d_ws, size_t ws_size,
                              hipStream_t stream) {
  const float* x    = (const float*)d_in[0];
  const float* cert = (const float*)d_in[1];
  const int*   perm = (const int*)d_in[2];
  const float* Wq = (const float*)d_in[3];
  const float* bq = (const float*)d_in[4];
  const float* Wk = (const float*)d_in[5];
  const float* bk = (const float*)d_in[6];
  const float* Wv = (const float*)d_in[7];
  const float* bv = (const float*)d_in[8];
  const float* Wo = (const float*)d_in[9];
  const float* bo = (const float*)d_in[10];

  float* out      = (float*)d_out;            // 917504
  float* cert_out = out + 917504;             // 65536
  float* perm_out = out + 983040;             // 65536

  float* ws = (float*)d_ws;
  float* Qt = ws;                    // 917504
  float* Kt = Qt + 917504;           // 917504
  float* Vt = Kt + 917504;           // 917504
  float* E1 = Vt + 917504;           // 65536
  float* E2 = E1 + 65536;            // 65536
  float* R  = E2 + 65536;            // 65536
  float* C  = R + 65536;             // 65536
  float* attn_o = C + 65536;         // 917504  (fallback footprint ends: 3,932,160 floats)
  float* vpart  = attn_o + 917504;   // 4,194,304 (fast path only)
  float* P0     = vpart + 4194304;   // G * 1,048,576 (fast path only)

  // choose batch-group size G by available workspace
  size_t base_f = 3932160u + 4194304u;
  size_t avail_f = (ws_size / 4 > base_f) ? (ws_size / 4 - base_f) : 0;
  int G = (int)(avail_f >> 20);                 // 1,048,576 floats per batch
  if (G >= 64) G = 64; else if (G >= 32) G = 32; else if (G >= 16) G = 16; else G = 0;

  qkv_kernel<<<256, 256, 0, stream>>>(x, Wq, bq, Wk, bk, Wv, bv, Qt, Kt, Vt, R, C);
  attn_kernel<<<4096, 512, 0, stream>>>(Qt, Kt, Vt, cert, E1, E2, attn_o, cert_out);
  proj_kernel<<<3584, 256, 0, stream>>>(attn_o, Wo, bo, out);

  if (G >= 16) {
    int logS = (G == 64) ? 5 : 6;               // keep vpart <= 4M floats
    int S = 1 << logS;
    for (int b0 = 0; b0 < 64; b0 += G) {
      p0pre_kernel<<<G * 32, 512, 0, stream>>>(Qt, Kt, E1, E2, P0, b0);
      for (int it = 0; it < 20; it++) {
        sink_fused<<<G << logS, 256, 0, stream>>>(P0, C, R, vpart, b0, G, logS);
        cupdate_kernel<<<G * 4, 256, 0, stream>>>(C, vpart, b0, G, S);
      }
      argmaxP_kernel<<<G * 128, 512, 0, stream>>>(P0, C, perm, perm_out, b0);
    }
  } else {
    for (int it = 0; it < 20; it++) {
      sinkA_kernel<<<2048, 512, 0, stream>>>(Qt, Kt, E1, E2, C, R);
      sinkB_kernel<<<2048, 512, 0, stream>>>(Qt, Kt, E1, E2, R, C);
    }
    argmax_kernel<<<8192, 512, 0, stream>>>(Qt, Kt, E1, E2, C, perm, perm_out);
  }
}

// Round 7
// 2176.883 us; speedup vs baseline: 1.5628x; 1.5628x over previous
//
#include <hip/hip_runtime.h>

#define EPSF    1e-10f
#define MAXENT  6.93147180559945286f   // ln(1024)
#define SCALEF  0.37796447300922720f   // 1/sqrt(7)

// ---------------- helpers ----------------
__device__ __forceinline__ float wave_sum(float v) {
#pragma unroll
  for (int off = 32; off > 0; off >>= 1) v += __shfl_xor(v, off);
  return v;
}
__device__ __forceinline__ void wave_sum2(float& a, float& b) {
#pragma unroll
  for (int off = 32; off > 0; off >>= 1) {
    a += __shfl_xor(a, off);
    b += __shfl_xor(b, off);
  }
}
__device__ __forceinline__ void fma4(float a, float4 b, float4& c) {
  c.x = fmaf(a, b.x, c.x); c.y = fmaf(a, b.y, c.y);
  c.z = fmaf(a, b.z, c.z); c.w = fmaf(a, b.w, c.w);
}
__device__ __forceinline__ float dot4(float4 a, float4 b, float acc) {
  acc = fmaf(a.x, b.x, acc); acc = fmaf(a.y, b.y, acc);
  acc = fmaf(a.z, b.z, acc); acc = fmaf(a.w, b.w, acc);
  return acc;
}
__device__ __forceinline__ float exp4sum(float4 s) {
  return __expf(s.x) + __expf(s.y) + __expf(s.z) + __expf(s.w);
}
// P0 = (E1*exp(s1) + E2*exp(s2) + EPS)^10, E_h = 0.5/L_h (no-max softmax; |s|<~12 so safe)
__device__ __forceinline__ float p0e(float s1, float s2, float E1, float E2) {
  float p = fmaf(E1, __expf(s1), fmaf(E2, __expf(s2), EPSF));
  float p2 = p * p, p4 = p2 * p2, p5 = p4 * p;
  return p5 * p5;
}

// ---------------- kernel 0: QKV projection (d-major, Q pre-scaled) + R/C init ----------------
__global__ __launch_bounds__(256) void qkv_kernel(
    const float* __restrict__ x,
    const float* __restrict__ Wq, const float* __restrict__ bq,
    const float* __restrict__ Wk, const float* __restrict__ bk,
    const float* __restrict__ Wv, const float* __restrict__ bv,
    float* __restrict__ Qt, float* __restrict__ Kt, float* __restrict__ Vt,
    float* __restrict__ R, float* __restrict__ C) {
  int row = blockIdx.x * 256 + threadIdx.x;     // 65536 rows
  int b = row >> 10, i = row & 1023;
  float xv[14];
#pragma unroll
  for (int k = 0; k < 14; k++) xv[k] = x[row * 14 + k];
#pragma unroll
  for (int d = 0; d < 14; d++) {
    float q = bq[d], kk = bk[d], vv = bv[d];
#pragma unroll
    for (int k = 0; k < 14; k++) {
      q  = fmaf(xv[k], Wq[d * 14 + k], q);
      kk = fmaf(xv[k], Wk[d * 14 + k], kk);
      vv = fmaf(xv[k], Wv[d * 14 + k], vv);
    }
    int o = b * 14336 + d * 1024 + i;
    Qt[o] = q * SCALEF;
    Kt[o] = kk; Vt[o] = vv;
  }
  R[row] = 1.0f;
  C[row] = 1.0f;
}

// ---------------- kernel 1: fused attention + entropy/certainty + E1/E2 ----------------
__global__ __launch_bounds__(512) void attn_kernel(
    const float* __restrict__ Qt, const float* __restrict__ Kt, const float* __restrict__ Vt,
    const float* __restrict__ cert_in,
    float* __restrict__ E1o, float* __restrict__ E2o,
    float* __restrict__ attn_o, float* __restrict__ cert_out) {
  __shared__ float4 Kl[3584];                   // 56 KB
  int b = blockIdx.x >> 6;
  int rg = blockIdx.x & 63;
  int tid = threadIdx.x;
  const float4* Ktb = (const float4*)(Kt + b * 14336);
  for (int idx = tid; idx < 3584; idx += 512) Kl[idx] = Ktb[idx];
  __syncthreads();

  int wave = tid >> 6, lane = tid & 63;
  int i0 = rg * 16 + wave * 2;
  float q0[14], q1[14];
#pragma unroll
  for (int d = 0; d < 14; d++) {
    q0[d] = Qt[b * 14336 + d * 1024 + i0];
    q1[d] = Qt[b * 14336 + d * 1024 + i0 + 1];
  }

  float L10 = 0.f, L20 = 0.f, L11 = 0.f, L21 = 0.f;
#pragma unroll
  for (int t = 0; t < 4; t++) {
    int g = t * 64 + lane;
    float4 kv[7];
#pragma unroll
    for (int d = 0; d < 7; d++) kv[d] = Kl[d * 256 + g];
    float4 sa = {0,0,0,0}, sb = {0,0,0,0};
#pragma unroll
    for (int d = 0; d < 7; d++) { fma4(q0[d], kv[d], sa); fma4(q1[d], kv[d], sb); }
    L10 += exp4sum(sa); L11 += exp4sum(sb);
#pragma unroll
    for (int d = 0; d < 7; d++) kv[d] = Kl[(d + 7) * 256 + g];
    sa = make_float4(0,0,0,0); sb = make_float4(0,0,0,0);
#pragma unroll
    for (int d = 0; d < 7; d++) { fma4(q0[d + 7], kv[d], sa); fma4(q1[d + 7], kv[d], sb); }
    L20 += exp4sum(sa); L21 += exp4sum(sb);
  }
  L10 = wave_sum(L10); L20 = wave_sum(L20);
  L11 = wave_sum(L11); L21 = wave_sum(L21);
  float i10 = 1.0f / L10, i20 = 1.0f / L20, i11 = 1.0f / L11, i21 = 1.0f / L21;

  float acc0[14], acc1[14];
#pragma unroll
  for (int d = 0; d < 14; d++) { acc0[d] = 0.f; acc1[d] = 0.f; }
  float ent0 = 0.f, ent1 = 0.f;
  const float4* Vtb = (const float4*)(Vt + b * 14336);
#pragma unroll
  for (int t = 0; t < 4; t++) {
    int g = t * 64 + lane;
    float4 kv[7];
#pragma unroll
    for (int d = 0; d < 7; d++) kv[d] = Kl[d * 256 + g];
    float4 sa = {0,0,0,0}, sb = {0,0,0,0};
#pragma unroll
    for (int d = 0; d < 7; d++) { fma4(q0[d], kv[d], sa); fma4(q1[d], kv[d], sb); }
    float4 e10 = make_float4(__expf(sa.x), __expf(sa.y), __expf(sa.z), __expf(sa.w));
    float4 e11 = make_float4(__expf(sb.x), __expf(sb.y), __expf(sb.z), __expf(sb.w));
#pragma unroll
    for (int d = 0; d < 7; d++) kv[d] = Kl[(d + 7) * 256 + g];
    sa = make_float4(0,0,0,0); sb = make_float4(0,0,0,0);
#pragma unroll
    for (int d = 0; d < 7; d++) { fma4(q0[d + 7], kv[d], sa); fma4(q1[d + 7], kv[d], sb); }
    float4 e20 = make_float4(__expf(sa.x), __expf(sa.y), __expf(sa.z), __expf(sa.w));
    float4 e21 = make_float4(__expf(sb.x), __expf(sb.y), __expf(sb.z), __expf(sb.w));
#pragma unroll
    for (int d = 0; d < 7; d++) {
      float4 vv = Vtb[d * 256 + g];
      acc0[d] += e10.x * vv.x + e10.y * vv.y + e10.z * vv.z + e10.w * vv.w;
      acc1[d] += e11.x * vv.x + e11.y * vv.y + e11.z * vv.z + e11.w * vv.w;
    }
#pragma unroll
    for (int d = 7; d < 14; d++) {
      float4 vv = Vtb[d * 256 + g];
      acc0[d] += e20.x * vv.x + e20.y * vv.y + e20.z * vv.z + e20.w * vv.w;
      acc1[d] += e21.x * vv.x + e21.y * vv.y + e21.z * vv.z + e21.w * vv.w;
    }
    float a;
    a = 0.5f * (e10.x * i10 + e20.x * i20); ent0 -= a * __logf(a + EPSF);
    a = 0.5f * (e10.y * i10 + e20.y * i20); ent0 -= a * __logf(a + EPSF);
    a = 0.5f * (e10.z * i10 + e20.z * i20); ent0 -= a * __logf(a + EPSF);
    a = 0.5f * (e10.w * i10 + e20.w * i20); ent0 -= a * __logf(a + EPSF);
    a = 0.5f * (e11.x * i11 + e21.x * i21); ent1 -= a * __logf(a + EPSF);
    a = 0.5f * (e11.y * i11 + e21.y * i21); ent1 -= a * __logf(a + EPSF);
    a = 0.5f * (e11.z * i11 + e21.z * i21); ent1 -= a * __logf(a + EPSF);
    a = 0.5f * (e11.w * i11 + e21.w * i21); ent1 -= a * __logf(a + EPSF);
  }
  ent0 = wave_sum(ent0); ent1 = wave_sum(ent1);
#pragma unroll
  for (int d = 0; d < 14; d++) { acc0[d] = wave_sum(acc0[d]); acc1[d] = wave_sum(acc1[d]); }

  if (lane == 0) {
    int row0 = b * 1024 + i0;
    E1o[row0] = 0.5f * i10;  E2o[row0] = 0.5f * i20;
    E1o[row0 + 1] = 0.5f * i11; E2o[row0 + 1] = 0.5f * i21;
#pragma unroll
    for (int d = 0; d < 14; d++) {
      attn_o[row0 * 14 + d] = acc0[d] * (d < 7 ? i10 : i20);
      attn_o[(row0 + 1) * 14 + d] = acc1[d] * (d < 7 ? i11 : i21);
    }
    cert_out[row0] = fmaxf(cert_in[row0], 1.0f / (1.0f + __expf(ent0 - MAXENT)));
    cert_out[row0 + 1] = fmaxf(cert_in[row0 + 1], 1.0f / (1.0f + __expf(ent1 - MAXENT)));
  }
}

// ---------------- kernel 2: output projection ----------------
__global__ __launch_bounds__(256) void proj_kernel(
    const float* __restrict__ attn_o, const float* __restrict__ Wo,
    const float* __restrict__ bo, float* __restrict__ out) {
  int idx = blockIdx.x * 256 + threadIdx.x;     // 917504 = 65536*14
  if (idx >= 917504) return;
  int row = idx / 14, d = idx - row * 14;
  float s = bo[d];
  const float* ar = attn_o + row * 14;
  const float* wr = Wo + d * 14;
#pragma unroll
  for (int k = 0; k < 14; k++) s = fmaf(ar[k], wr[k], s);
  out[idx] = s;
}

// ================= FAST PATH: grouped materialized P0 =================

// precompute P0 for G batches starting at b0; grid = G*32 blocks, 32 rows/block
__global__ __launch_bounds__(512) void p0pre_kernel(
    const float* __restrict__ Qt, const float* __restrict__ Kt,
    const float* __restrict__ E1, const float* __restrict__ E2,
    float* __restrict__ P0, int b0) {
  __shared__ float4 Kl[3584];
  int gb = blockIdx.x >> 5, blk = blockIdx.x & 31;
  int b = b0 + gb;
  int tid = threadIdx.x;
  const float4* Ktb = (const float4*)(Kt + b * 14336);
  for (int idx = tid; idx < 3584; idx += 512) Kl[idx] = Ktb[idx];
  __syncthreads();

  int wave = tid >> 6, lane = tid & 63;
  int i0 = blk * 32 + wave * 4;
  float q[4][14], e1r[4], e2r[4];
#pragma unroll
  for (int rr = 0; rr < 4; rr++) {
#pragma unroll
    for (int d = 0; d < 14; d++) q[rr][d] = Qt[b * 14336 + d * 1024 + i0 + rr];
    e1r[rr] = E1[b * 1024 + i0 + rr];
    e2r[rr] = E2[b * 1024 + i0 + rr];
  }
  float4* P0f4 = (float4*)P0;
#pragma unroll
  for (int t = 0; t < 4; t++) {
    int g = t * 64 + lane;
    float4 kv[14];
#pragma unroll
    for (int d = 0; d < 14; d++) kv[d] = Kl[d * 256 + g];
#pragma unroll
    for (int rr = 0; rr < 4; rr++) {
      float4 s1 = {0,0,0,0}, s2 = {0,0,0,0};
#pragma unroll
      for (int d = 0; d < 7; d++)  fma4(q[rr][d], kv[d], s1);
#pragma unroll
      for (int d = 7; d < 14; d++) fma4(q[rr][d], kv[d], s2);
      float4 pv;
      pv.x = p0e(s1.x, s2.x, e1r[rr], e2r[rr]);
      pv.y = p0e(s1.y, s2.y, e1r[rr], e2r[rr]);
      pv.z = p0e(s1.z, s2.z, e1r[rr], e2r[rr]);
      pv.w = p0e(s1.w, s2.w, e1r[rr], e2r[rr]);
      P0f4[(size_t)(gb * 1024 + i0 + rr) * 256 + g] = pv;
    }
  }
}

// fused Sinkhorn iteration v3: 512 thr = 8 waves, S=16 slices (compile-time),
// 8 rows/wave processed in software-pipelined PAIRS (prefetch next pair's loads
// before consuming current pair -> depth-2 MLP; round-5's runtime loop serialized
// the ~800-cycle load->reduce chain per row).
#define SINK_LOGS 4
#define SINK_S    16
__global__ __launch_bounds__(512) void sink_fused(
    const float* __restrict__ P0, const float* __restrict__ Cg,
    float* __restrict__ R, float* __restrict__ vpart,
    int b0, int G) {
  __shared__ float vbuf[1024];
  int tid = threadIdx.x;
  for (int idx = tid; idx < 1024; idx += 512) vbuf[idx] = 0.f;
  __syncthreads();
  int gb = blockIdx.x >> SINK_LOGS, slice = blockIdx.x & (SINK_S - 1);
  int b = b0 + gb;
  int wave = tid >> 6, lane = tid & 63;
  int i0 = slice * 64 + wave * 8;               // 64 rows/block, 8 rows/wave
  int rbase = b * 1024 + i0;
  const float4* Cb = (const float4*)(Cg + b * 1024);
  int l0 = lane, l1 = 64 + lane, l2 = 128 + lane, l3 = 192 + lane;
  float4 c0 = Cb[l0], c1 = Cb[l1], c2 = Cb[l2], c3 = Cb[l3];
  float4 v0 = {0,0,0,0}, v1 = {0,0,0,0}, v2 = {0,0,0,0}, v3 = {0,0,0,0};
  const float4* base = (const float4*)P0 + (size_t)(gb * 1024 + i0) * 256;

  // prologue: load pair 0 (rows 0,1)
  float4 a0 = base[l0], a1 = base[l1], a2 = base[l2], a3 = base[l3];
  float4 b0f = base[256 + l0], b1f = base[256 + l1], b2f = base[256 + l2], b3f = base[256 + l3];

#pragma unroll
  for (int r = 0; r < 8; r += 2) {
    float4 na0, na1, na2, na3, nb0, nb1, nb2, nb3;
    if (r + 2 < 8) {                            // prefetch next pair (issues before waits below)
      const float4* nxt = base + (r + 2) * 256;
      na0 = nxt[l0]; na1 = nxt[l1]; na2 = nxt[l2]; na3 = nxt[l3];
      nb0 = nxt[256 + l0]; nb1 = nxt[256 + l1]; nb2 = nxt[256 + l2]; nb3 = nxt[256 + l3];
    }
    float rva = R[rbase + r], rvb = R[rbase + r + 1];
    float ua = dot4(a3, c3, dot4(a2, c2, dot4(a1, c1, dot4(a0, c0, 0.f))));
    float ub = dot4(b3f, c3, dot4(b2f, c2, dot4(b1f, c1, dot4(b0f, c0, 0.f))));
    wave_sum2(ua, ub);
    rva = fminf(rva / fmaf(rva, ua, EPSF), 1e37f);
    rvb = fminf(rvb / fmaf(rvb, ub, EPSF), 1e37f);
    if (lane == 0) { R[rbase + r] = rva; R[rbase + r + 1] = rvb; }
    fma4(rva, a0, v0); fma4(rva, a1, v1); fma4(rva, a2, v2); fma4(rva, a3, v3);
    fma4(rvb, b0f, v0); fma4(rvb, b1f, v1); fma4(rvb, b2f, v2); fma4(rvb, b3f, v3);
    if (r + 2 < 8) {
      a0 = na0; a1 = na1; a2 = na2; a3 = na3;
      b0f = nb0; b1f = nb1; b2f = nb2; b3f = nb3;
    }
  }
  // merge 8 waves' column partials in LDS
  atomicAdd(&vbuf[4 * lane + 0], v0.x); atomicAdd(&vbuf[4 * lane + 1], v0.y);
  atomicAdd(&vbuf[4 * lane + 2], v0.z); atomicAdd(&vbuf[4 * lane + 3], v0.w);
  atomicAdd(&vbuf[256 + 4 * lane + 0], v1.x); atomicAdd(&vbuf[256 + 4 * lane + 1], v1.y);
  atomicAdd(&vbuf[256 + 4 * lane + 2], v1.z); atomicAdd(&vbuf[256 + 4 * lane + 3], v1.w);
  atomicAdd(&vbuf[512 + 4 * lane + 0], v2.x); atomicAdd(&vbuf[512 + 4 * lane + 1], v2.y);
  atomicAdd(&vbuf[512 + 4 * lane + 2], v2.z); atomicAdd(&vbuf[512 + 4 * lane + 3], v2.w);
  atomicAdd(&vbuf[768 + 4 * lane + 0], v3.x); atomicAdd(&vbuf[768 + 4 * lane + 1], v3.y);
  atomicAdd(&vbuf[768 + 4 * lane + 2], v3.z); atomicAdd(&vbuf[768 + 4 * lane + 3], v3.w);
  __syncthreads();
  float* vp = vpart + (size_t)(slice * G + gb) * 1024;
  for (int idx = tid; idx < 1024; idx += 512) vp[idx] = vbuf[idx];
}

// C update: v = sum of 16 slice partials (unrolled, independent loads), then C update
__global__ __launch_bounds__(256) void cupdate_kernel(
    float* __restrict__ C, const float* __restrict__ vpart, int b0, int G) {
  int idx = blockIdx.x * 256 + threadIdx.x;     // < G*1024
  int gb = idx >> 10, j = idx & 1023;
  const float* vp = vpart + gb * 1024 + j;
  float v = 0.f;
#pragma unroll
  for (int s = 0; s < SINK_S; s++) v += vp[(size_t)s * G * 1024];
  int o = (b0 + gb) * 1024 + j;
  float cv = C[o];
  C[o] = fminf(cv / fmaf(cv, v, EPSF), 1e37f);
}

// argmax over stored P0 * C + permutation gather; grid = G*128
__global__ __launch_bounds__(512) void argmaxP_kernel(
    const float* __restrict__ P0, const float* __restrict__ Cg,
    const int* __restrict__ perm, float* __restrict__ perm_out, int b0) {
  int gb = blockIdx.x >> 7, rg = blockIdx.x & 127;
  int b = b0 + gb;
  int tid = threadIdx.x;
  int wave = tid >> 6, lane = tid & 63;
  int i = rg * 8 + wave;
  const float4* Cb = (const float4*)(Cg + b * 1024);
  const float4* Prow = (const float4*)P0 + (size_t)(gb * 1024 + i) * 256;

  float best = -1.0f;
  int bj = 0;
#pragma unroll
  for (int t = 0; t < 4; t++) {
    int g = t * 64 + lane;
    float4 pv = Prow[g], cv = Cb[g];
    float val;
    val = pv.x * cv.x; if (val > best) { best = val; bj = 4 * g + 0; }
    val = pv.y * cv.y; if (val > best) { best = val; bj = 4 * g + 1; }
    val = pv.z * cv.z; if (val > best) { best = val; bj = 4 * g + 2; }
    val = pv.w * cv.w; if (val > best) { best = val; bj = 4 * g + 3; }
  }
#pragma unroll
  for (int off = 32; off > 0; off >>= 1) {
    float ob = __shfl_xor(best, off);
    int oj = __shfl_xor(bj, off);
    if (ob > best || (ob == best && oj < bj)) { best = ob; bj = oj; }
  }
  if (lane == 0) perm_out[b * 1024 + i] = (float)perm[b * 1024 + bj];
}

// ================= FALLBACK PATH (round-3, recompute) =================

__global__ __launch_bounds__(512) void sinkA_kernel(
    const float* __restrict__ Qt, const float* __restrict__ Kt,
    const float* __restrict__ E1, const float* __restrict__ E2,
    const float* __restrict__ C, float* __restrict__ R) {
  __shared__ float4 Kl[3584];
  int b = blockIdx.x >> 5, blk = blockIdx.x & 31;
  int tid = threadIdx.x;
  const float4* Ktb = (const float4*)(Kt + b * 14336);
  for (int idx = tid; idx < 3584; idx += 512) Kl[idx] = Ktb[idx];
  __syncthreads();
  int wave = tid >> 6, lane = tid & 63;
  int i0 = blk * 32 + wave * 4;
  float q[4][14], e1r[4], e2r[4], u[4];
#pragma unroll
  for (int rr = 0; rr < 4; rr++) {
#pragma unroll
    for (int d = 0; d < 14; d++) q[rr][d] = Qt[b * 14336 + d * 1024 + i0 + rr];
    e1r[rr] = E1[b * 1024 + i0 + rr];
    e2r[rr] = E2[b * 1024 + i0 + rr];
    u[rr] = 0.f;
  }
  const float4* Cb = (const float4*)(C + b * 1024);
#pragma unroll
  for (int t = 0; t < 4; t++) {
    int g = t * 64 + lane;
    float4 kv[14];
#pragma unroll
    for (int d = 0; d < 14; d++) kv[d] = Kl[d * 256 + g];
    float4 cv = Cb[g];
#pragma unroll
    for (int rr = 0; rr < 4; rr++) {
      float4 s1 = {0,0,0,0}, s2 = {0,0,0,0};
#pragma unroll
      for (int d = 0; d < 7; d++)  fma4(q[rr][d], kv[d], s1);
#pragma unroll
      for (int d = 7; d < 14; d++) fma4(q[rr][d], kv[d], s2);
      u[rr] += p0e(s1.x, s2.x, e1r[rr], e2r[rr]) * cv.x;
      u[rr] += p0e(s1.y, s2.y, e1r[rr], e2r[rr]) * cv.y;
      u[rr] += p0e(s1.z, s2.z, e1r[rr], e2r[rr]) * cv.z;
      u[rr] += p0e(s1.w, s2.w, e1r[rr], e2r[rr]) * cv.w;
    }
  }
#pragma unroll
  for (int rr = 0; rr < 4; rr++) u[rr] = wave_sum(u[rr]);
  if (lane == 0) {
#pragma unroll
    for (int rr = 0; rr < 4; rr++) {
      int o = b * 1024 + i0 + rr;
      float rv = R[o];
      R[o] = fminf(rv / fmaf(rv, u[rr], EPSF), 1e37f);
    }
  }
}

__global__ __launch_bounds__(512) void sinkB_kernel(
    const float* __restrict__ Qt, const float* __restrict__ Kt,
    const float* __restrict__ E1, const float* __restrict__ E2,
    const float* __restrict__ R, float* __restrict__ C) {
  __shared__ float4 Ql[3584];
  int b = blockIdx.x >> 5, blk = blockIdx.x & 31;
  int tid = threadIdx.x;
  const float4* Qtb = (const float4*)(Qt + b * 14336);
  for (int idx = tid; idx < 3584; idx += 512) Ql[idx] = Qtb[idx];
  __syncthreads();
  int wave = tid >> 6, lane = tid & 63;
  int j0 = blk * 32 + wave * 4;
  float kk[4][14], v[4];
#pragma unroll
  for (int rr = 0; rr < 4; rr++) {
#pragma unroll
    for (int d = 0; d < 14; d++) kk[rr][d] = Kt[b * 14336 + d * 1024 + j0 + rr];
    v[rr] = 0.f;
  }
  const float4* E1b = (const float4*)(E1 + b * 1024);
  const float4* E2b = (const float4*)(E2 + b * 1024);
  const float4* Rb  = (const float4*)(R + b * 1024);
#pragma unroll
  for (int t = 0; t < 4; t++) {
    int g = t * 64 + lane;
    float4 qv[14];
#pragma unroll
    for (int d = 0; d < 14; d++) qv[d] = Ql[d * 256 + g];
    float4 e1v = E1b[g], e2v = E2b[g], rv = Rb[g];
#pragma unroll
    for (int rr = 0; rr < 4; rr++) {
      float4 s1 = {0,0,0,0}, s2 = {0,0,0,0};
#pragma unroll
      for (int d = 0; d < 7; d++)  fma4(kk[rr][d], qv[d], s1);
#pragma unroll
      for (int d = 7; d < 14; d++) fma4(kk[rr][d], qv[d], s2);
      v[rr] += p0e(s1.x, s2.x, e1v.x, e2v.x) * rv.x;
      v[rr] += p0e(s1.y, s2.y, e1v.y, e2v.y) * rv.y;
      v[rr] += p0e(s1.z, s2.z, e1v.z, e2v.z) * rv.z;
      v[rr] += p0e(s1.w, s2.w, e1v.w, e2v.w) * rv.w;
    }
  }
#pragma unroll
  for (int rr = 0; rr < 4; rr++) v[rr] = wave_sum(v[rr]);
  if (lane == 0) {
#pragma unroll
    for (int rr = 0; rr < 4; rr++) {
      int o = b * 1024 + j0 + rr;
      float cv = C[o];
      C[o] = fminf(cv / fmaf(cv, v[rr], EPSF), 1e37f);
    }
  }
}

__global__ __launch_bounds__(512) void argmax_kernel(
    const float* __restrict__ Qt, const float* __restrict__ Kt,
    const float* __restrict__ E1, const float* __restrict__ E2,
    const float* __restrict__ C, const int* __restrict__ perm,
    float* __restrict__ perm_out) {
  __shared__ float4 Kl[3584];
  int b = blockIdx.x >> 7, rg = blockIdx.x & 127;
  int tid = threadIdx.x;
  const float4* Ktb = (const float4*)(Kt + b * 14336);
  for (int idx = tid; idx < 3584; idx += 512) Kl[idx] = Ktb[idx];
  __syncthreads();
  int wave = tid >> 6, lane = tid & 63;
  int i = rg * 8 + wave;
  int row = b * 1024 + i;
  float q[14];
#pragma unroll
  for (int d = 0; d < 14; d++) q[d] = Qt[b * 14336 + d * 1024 + i];
  float e1r = E1[row], e2r = E2[row];
  const float4* Cb = (const float4*)(C + b * 1024);
  float best = -1.0f;
  int bj = 0;
#pragma unroll
  for (int t = 0; t < 4; t++) {
    int g = t * 64 + lane;
    float4 kv[14];
#pragma unroll
    for (int d = 0; d < 14; d++) kv[d] = Kl[d * 256 + g];
    float4 cv = Cb[g];
    float4 s1 = {0,0,0,0}, s2 = {0,0,0,0};
#pragma unroll
    for (int d = 0; d < 7; d++)  fma4(q[d], kv[d], s1);
#pragma unroll
    for (int d = 7; d < 14; d++) fma4(q[d], kv[d], s2);
    float val;
    val = p0e(s1.x, s2.x, e1r, e2r) * cv.x; if (val > best) { best = val; bj = 4 * g + 0; }
    val = p0e(s1.y, s2.y, e1r, e2r) * cv.y; if (val > best) { best = val; bj = 4 * g + 1; }
    val = p0e(s1.z, s2.z, e1r, e2r) * cv.z; if (val > best) { best = val; bj = 4 * g + 2; }
    val = p0e(s1.w, s2.w, e1r, e2r) * cv.w; if (val > best) { best = val; bj = 4 * g + 3; }
  }
#pragma unroll
  for (int off = 32; off > 0; off >>= 1) {
    float ob = __shfl_xor(best, off);
    int oj = __shfl_xor(bj, off);
    if (ob > best || (ob == best && oj < bj)) { best = ob; bj = oj; }
  }
  if (lane == 0) perm_out[row] = (float)perm[b * 1024 + bj];
}

// ---------------- launch ----------------
extern "C" void kernel_launch(void* const* d_in, const int* in_sizes, int n_in,
                              void* d_out, int out_size, void* d_ws, size_t ws_size,
                              hipStream_t stream) {
  const float* x    = (const float*)d_in[0];
  const float* cert = (const float*)d_in[1];
  const int*   perm = (const int*)d_in[2];
  const float* Wq = (const float*)d_in[3];
  const float* bq = (const float*)d_in[4];
  const float* Wk = (const float*)d_in[5];
  const float* bk = (const float*)d_in[6];
  const float* Wv = (const float*)d_in[7];
  const float* bv = (const float*)d_in[8];
  const float* Wo = (const float*)d_in[9];
  const float* bo = (const float*)d_in[10];

  float* out      = (float*)d_out;            // 917504
  float* cert_out = out + 917504;             // 65536
  float* perm_out = out + 983040;             // 65536

  float* ws = (float*)d_ws;
  float* Qt = ws;                    // 917504
  float* Kt = Qt + 917504;           // 917504
  float* Vt = Kt + 917504;           // 917504
  float* E1 = Vt + 917504;           // 65536
  float* E2 = E1 + 65536;            // 65536
  float* R  = E2 + 65536;            // 65536
  float* C  = R + 65536;             // 65536
  float* attn_o = C + 65536;         // 917504  (fallback footprint ends: 3,932,160 floats)
  float* vpart  = attn_o + 917504;   // 1,048,576 (fast path only; S=16 x 64 x 1024 max)
  float* P0     = vpart + 1048576;   // G * 1,048,576 (fast path only)

  // choose batch-group size G by available workspace
  size_t base_f = 3932160u + 1048576u;
  size_t avail_f = (ws_size / 4 > base_f) ? (ws_size / 4 - base_f) : 0;
  int G = (int)(avail_f >> 20);                 // 1,048,576 floats per batch
  if (G >= 64) G = 64; else if (G >= 32) G = 32; else if (G >= 16) G = 16; else G = 0;

  qkv_kernel<<<256, 256, 0, stream>>>(x, Wq, bq, Wk, bk, Wv, bv, Qt, Kt, Vt, R, C);
  attn_kernel<<<4096, 512, 0, stream>>>(Qt, Kt, Vt, cert, E1, E2, attn_o, cert_out);
  proj_kernel<<<3584, 256, 0, stream>>>(attn_o, Wo, bo, out);

  if (G >= 16) {
    for (int b0 = 0; b0 < 64; b0 += G) {
      p0pre_kernel<<<G * 32, 512, 0, stream>>>(Qt, Kt, E1, E2, P0, b0);
      for (int it = 0; it < 20; it++) {
        sink_fused<<<G * SINK_S, 512, 0, stream>>>(P0, C, R, vpart, b0, G);
        cupdate_kernel<<<G * 4, 256, 0, stream>>>(C, vpart, b0, G);
      }
      argmaxP_kernel<<<G * 128, 512, 0, stream>>>(P0, C, perm, perm_out, b0);
    }
  } else {
    for (int it = 0; it < 20; it++) {
      sinkA_kernel<<<2048, 512, 0, stream>>>(Qt, Kt, E1, E2, C, R);
      sinkB_kernel<<<2048, 512, 0, stream>>>(Qt, Kt, E1, E2, R, C);
    }
    argmax_kernel<<<8192, 512, 0, stream>>>(Qt, Kt, E1, E2, C, perm, perm_out);
  }
}

// Round 8
// 1426.380 us; speedup vs baseline: 2.3851x; 1.5262x over previous
//
#include <hip/hip_runtime.h>

#define EPSF    1e-10f
#define MAXENT  6.93147180559945286f   // ln(1024)
#define SCALEF  0.37796447300922720f   // 1/sqrt(7)

// ---------------- helpers ----------------
__device__ __forceinline__ float wave_sum(float v) {
#pragma unroll
  for (int off = 32; off > 0; off >>= 1) v += __shfl_xor(v, off);
  return v;
}
__device__ __forceinline__ void wave_sum2(float& a, float& b) {
#pragma unroll
  for (int off = 32; off > 0; off >>= 1) {
    a += __shfl_xor(a, off);
    b += __shfl_xor(b, off);
  }
}
__device__ __forceinline__ void fma4(float a, float4 b, float4& c) {
  c.x = fmaf(a, b.x, c.x); c.y = fmaf(a, b.y, c.y);
  c.z = fmaf(a, b.z, c.z); c.w = fmaf(a, b.w, c.w);
}
__device__ __forceinline__ float dot4(float4 a, float4 b, float acc) {
  acc = fmaf(a.x, b.x, acc); acc = fmaf(a.y, b.y, acc);
  acc = fmaf(a.z, b.z, acc); acc = fmaf(a.w, b.w, acc);
  return acc;
}
__device__ __forceinline__ float exp4sum(float4 s) {
  return __expf(s.x) + __expf(s.y) + __expf(s.z) + __expf(s.w);
}
// P0 = (E1*exp(s1) + E2*exp(s2) + EPS)^10, E_h = 0.5/L_h (no-max softmax; |s|<~12 so safe)
__device__ __forceinline__ float p0e(float s1, float s2, float E1, float E2) {
  float p = fmaf(E1, __expf(s1), fmaf(E2, __expf(s2), EPSF));
  float p2 = p * p, p4 = p2 * p2, p5 = p4 * p;
  return p5 * p5;
}

// ---------------- kernel 0: QKV projection (d-major, Q pre-scaled) + R/C init ----------------
__global__ __launch_bounds__(256) void qkv_kernel(
    const float* __restrict__ x,
    const float* __restrict__ Wq, const float* __restrict__ bq,
    const float* __restrict__ Wk, const float* __restrict__ bk,
    const float* __restrict__ Wv, const float* __restrict__ bv,
    float* __restrict__ Qt, float* __restrict__ Kt, float* __restrict__ Vt,
    float* __restrict__ R, float* __restrict__ CA, float* __restrict__ CB) {
  int row = blockIdx.x * 256 + threadIdx.x;     // 65536 rows
  int b = row >> 10, i = row & 1023;
  float xv[14];
#pragma unroll
  for (int k = 0; k < 14; k++) xv[k] = x[row * 14 + k];
#pragma unroll
  for (int d = 0; d < 14; d++) {
    float q = bq[d], kk = bk[d], vv = bv[d];
#pragma unroll
    for (int k = 0; k < 14; k++) {
      q  = fmaf(xv[k], Wq[d * 14 + k], q);
      kk = fmaf(xv[k], Wk[d * 14 + k], kk);
      vv = fmaf(xv[k], Wv[d * 14 + k], vv);
    }
    int o = b * 14336 + d * 1024 + i;
    Qt[o] = q * SCALEF;
    Kt[o] = kk; Vt[o] = vv;
  }
  R[row] = 1.0f;
  CA[row] = 1.0f;
  CB[row] = 1.0f;
}

// ---------------- kernel 1: fused attention + entropy/certainty + E1/E2 ----------------
__global__ __launch_bounds__(512) void attn_kernel(
    const float* __restrict__ Qt, const float* __restrict__ Kt, const float* __restrict__ Vt,
    const float* __restrict__ cert_in,
    float* __restrict__ E1o, float* __restrict__ E2o,
    float* __restrict__ attn_o, float* __restrict__ cert_out) {
  __shared__ float4 Kl[3584];                   // 56 KB
  int b = blockIdx.x >> 6;
  int rg = blockIdx.x & 63;
  int tid = threadIdx.x;
  const float4* Ktb = (const float4*)(Kt + b * 14336);
  for (int idx = tid; idx < 3584; idx += 512) Kl[idx] = Ktb[idx];
  __syncthreads();

  int wave = tid >> 6, lane = tid & 63;
  int i0 = rg * 16 + wave * 2;
  float q0[14], q1[14];
#pragma unroll
  for (int d = 0; d < 14; d++) {
    q0[d] = Qt[b * 14336 + d * 1024 + i0];
    q1[d] = Qt[b * 14336 + d * 1024 + i0 + 1];
  }

  float L10 = 0.f, L20 = 0.f, L11 = 0.f, L21 = 0.f;
#pragma unroll
  for (int t = 0; t < 4; t++) {
    int g = t * 64 + lane;
    float4 kv[7];
#pragma unroll
    for (int d = 0; d < 7; d++) kv[d] = Kl[d * 256 + g];
    float4 sa = {0,0,0,0}, sb = {0,0,0,0};
#pragma unroll
    for (int d = 0; d < 7; d++) { fma4(q0[d], kv[d], sa); fma4(q1[d], kv[d], sb); }
    L10 += exp4sum(sa); L11 += exp4sum(sb);
#pragma unroll
    for (int d = 0; d < 7; d++) kv[d] = Kl[(d + 7) * 256 + g];
    sa = make_float4(0,0,0,0); sb = make_float4(0,0,0,0);
#pragma unroll
    for (int d = 0; d < 7; d++) { fma4(q0[d + 7], kv[d], sa); fma4(q1[d + 7], kv[d], sb); }
    L20 += exp4sum(sa); L21 += exp4sum(sb);
  }
  L10 = wave_sum(L10); L20 = wave_sum(L20);
  L11 = wave_sum(L11); L21 = wave_sum(L21);
  float i10 = 1.0f / L10, i20 = 1.0f / L20, i11 = 1.0f / L11, i21 = 1.0f / L21;

  float acc0[14], acc1[14];
#pragma unroll
  for (int d = 0; d < 14; d++) { acc0[d] = 0.f; acc1[d] = 0.f; }
  float ent0 = 0.f, ent1 = 0.f;
  const float4* Vtb = (const float4*)(Vt + b * 14336);
#pragma unroll
  for (int t = 0; t < 4; t++) {
    int g = t * 64 + lane;
    float4 kv[7];
#pragma unroll
    for (int d = 0; d < 7; d++) kv[d] = Kl[d * 256 + g];
    float4 sa = {0,0,0,0}, sb = {0,0,0,0};
#pragma unroll
    for (int d = 0; d < 7; d++) { fma4(q0[d], kv[d], sa); fma4(q1[d], kv[d], sb); }
    float4 e10 = make_float4(__expf(sa.x), __expf(sa.y), __expf(sa.z), __expf(sa.w));
    float4 e11 = make_float4(__expf(sb.x), __expf(sb.y), __expf(sb.z), __expf(sb.w));
#pragma unroll
    for (int d = 0; d < 7; d++) kv[d] = Kl[(d + 7) * 256 + g];
    sa = make_float4(0,0,0,0); sb = make_float4(0,0,0,0);
#pragma unroll
    for (int d = 0; d < 7; d++) { fma4(q0[d + 7], kv[d], sa); fma4(q1[d + 7], kv[d], sb); }
    float4 e20 = make_float4(__expf(sa.x), __expf(sa.y), __expf(sa.z), __expf(sa.w));
    float4 e21 = make_float4(__expf(sb.x), __expf(sb.y), __expf(sb.z), __expf(sb.w));
#pragma unroll
    for (int d = 0; d < 7; d++) {
      float4 vv = Vtb[d * 256 + g];
      acc0[d] += e10.x * vv.x + e10.y * vv.y + e10.z * vv.z + e10.w * vv.w;
      acc1[d] += e11.x * vv.x + e11.y * vv.y + e11.z * vv.z + e11.w * vv.w;
    }
#pragma unroll
    for (int d = 7; d < 14; d++) {
      float4 vv = Vtb[d * 256 + g];
      acc0[d] += e20.x * vv.x + e20.y * vv.y + e20.z * vv.z + e20.w * vv.w;
      acc1[d] += e21.x * vv.x + e21.y * vv.y + e21.z * vv.z + e21.w * vv.w;
    }
    float a;
    a = 0.5f * (e10.x * i10 + e20.x * i20); ent0 -= a * __logf(a + EPSF);
    a = 0.5f * (e10.y * i10 + e20.y * i20); ent0 -= a * __logf(a + EPSF);
    a = 0.5f * (e10.z * i10 + e20.z * i20); ent0 -= a * __logf(a + EPSF);
    a = 0.5f * (e10.w * i10 + e20.w * i20); ent0 -= a * __logf(a + EPSF);
    a = 0.5f * (e11.x * i11 + e21.x * i21); ent1 -= a * __logf(a + EPSF);
    a = 0.5f * (e11.y * i11 + e21.y * i21); ent1 -= a * __logf(a + EPSF);
    a = 0.5f * (e11.z * i11 + e21.z * i21); ent1 -= a * __logf(a + EPSF);
    a = 0.5f * (e11.w * i11 + e21.w * i21); ent1 -= a * __logf(a + EPSF);
  }
  ent0 = wave_sum(ent0); ent1 = wave_sum(ent1);
#pragma unroll
  for (int d = 0; d < 14; d++) { acc0[d] = wave_sum(acc0[d]); acc1[d] = wave_sum(acc1[d]); }

  if (lane == 0) {
    int row0 = b * 1024 + i0;
    E1o[row0] = 0.5f * i10;  E2o[row0] = 0.5f * i20;
    E1o[row0 + 1] = 0.5f * i11; E2o[row0 + 1] = 0.5f * i21;
#pragma unroll
    for (int d = 0; d < 14; d++) {
      attn_o[row0 * 14 + d] = acc0[d] * (d < 7 ? i10 : i20);
      attn_o[(row0 + 1) * 14 + d] = acc1[d] * (d < 7 ? i11 : i21);
    }
    cert_out[row0] = fmaxf(cert_in[row0], 1.0f / (1.0f + __expf(ent0 - MAXENT)));
    cert_out[row0 + 1] = fmaxf(cert_in[row0 + 1], 1.0f / (1.0f + __expf(ent1 - MAXENT)));
  }
}

// ---------------- kernel 2: output projection ----------------
__global__ __launch_bounds__(256) void proj_kernel(
    const float* __restrict__ attn_o, const float* __restrict__ Wo,
    const float* __restrict__ bo, float* __restrict__ out) {
  int idx = blockIdx.x * 256 + threadIdx.x;     // 917504 = 65536*14
  if (idx >= 917504) return;
  int row = idx / 14, d = idx - row * 14;
  float s = bo[d];
  const float* ar = attn_o + row * 14;
  const float* wr = Wo + d * 14;
#pragma unroll
  for (int k = 0; k < 14; k++) s = fmaf(ar[k], wr[k], s);
  out[idx] = s;
}

// ================= FAST PATH: grouped materialized P0 =================

// precompute P0 for G batches starting at b0; grid = G*32 blocks, 32 rows/block
__global__ __launch_bounds__(512) void p0pre_kernel(
    const float* __restrict__ Qt, const float* __restrict__ Kt,
    const float* __restrict__ E1, const float* __restrict__ E2,
    float* __restrict__ P0, int b0) {
  __shared__ float4 Kl[3584];
  int gb = blockIdx.x >> 5, blk = blockIdx.x & 31;
  int b = b0 + gb;
  int tid = threadIdx.x;
  const float4* Ktb = (const float4*)(Kt + b * 14336);
  for (int idx = tid; idx < 3584; idx += 512) Kl[idx] = Ktb[idx];
  __syncthreads();

  int wave = tid >> 6, lane = tid & 63;
  int i0 = blk * 32 + wave * 4;
  float q[4][14], e1r[4], e2r[4];
#pragma unroll
  for (int rr = 0; rr < 4; rr++) {
#pragma unroll
    for (int d = 0; d < 14; d++) q[rr][d] = Qt[b * 14336 + d * 1024 + i0 + rr];
    e1r[rr] = E1[b * 1024 + i0 + rr];
    e2r[rr] = E2[b * 1024 + i0 + rr];
  }
  float4* P0f4 = (float4*)P0;
#pragma unroll
  for (int t = 0; t < 4; t++) {
    int g = t * 64 + lane;
    float4 kv[14];
#pragma unroll
    for (int d = 0; d < 14; d++) kv[d] = Kl[d * 256 + g];
#pragma unroll
    for (int rr = 0; rr < 4; rr++) {
      float4 s1 = {0,0,0,0}, s2 = {0,0,0,0};
#pragma unroll
      for (int d = 0; d < 7; d++)  fma4(q[rr][d], kv[d], s1);
#pragma unroll
      for (int d = 7; d < 14; d++) fma4(q[rr][d], kv[d], s2);
      float4 pv;
      pv.x = p0e(s1.x, s2.x, e1r[rr], e2r[rr]);
      pv.y = p0e(s1.y, s2.y, e1r[rr], e2r[rr]);
      pv.z = p0e(s1.z, s2.z, e1r[rr], e2r[rr]);
      pv.w = p0e(s1.w, s2.w, e1r[rr], e2r[rr]);
      P0f4[(size_t)(gb * 1024 + i0 + rr) * 256 + g] = pv;
    }
  }
}

// fused Sinkhorn iteration v4: C-update folded in (each block redundantly computes
// C_{it-1} from previous iteration's v-partials; slice-0 persists it). vpart and C
// are ping-ponged between launches -> 1 launch per Sinkhorn iteration.
#define SINK_LOGS 4
#define SINK_S    16
__global__ __launch_bounds__(512) void sink_fused(
    const float* __restrict__ P0, const float* __restrict__ Cin,
    float* __restrict__ Cout, float* __restrict__ R,
    const float* __restrict__ vprev, float* __restrict__ vcur,
    int b0, int G) {
  __shared__ float Cl[1024];                    // C_{it-1} for this batch
  __shared__ float vbuf[8192];                  // per-wave v partials (32 KB)
  int tid = threadIdx.x;
  int gb = blockIdx.x >> SINK_LOGS, slice = blockIdx.x & (SINK_S - 1);
  int b = b0 + gb;

  // step A: recompute C_{it-1} (redundant per block; deterministic + identical order)
  for (int col = tid; col < 1024; col += 512) {
    float cv = Cin[b * 1024 + col];
    if (vprev) {
      const float* vp = vprev + gb * 1024 + col;
      float v = 0.f;
#pragma unroll
      for (int s = 0; s < SINK_S; s++) v += vp[(size_t)s * G * 1024];
      cv = fminf(cv / fmaf(cv, v, EPSF), 1e37f);
      if (slice == 0) Cout[b * 1024 + col] = cv;
    }
    Cl[col] = cv;
  }
  __syncthreads();

  int wave = tid >> 6, lane = tid & 63;
  int i0 = slice * 64 + wave * 8;               // 64 rows/block, 8 rows/wave
  int rbase = b * 1024 + i0;
  int l0 = lane, l1 = 64 + lane, l2 = 128 + lane, l3 = 192 + lane;
  const float4* Cl4 = (const float4*)Cl;
  float4 c0 = Cl4[l0], c1 = Cl4[l1], c2 = Cl4[l2], c3 = Cl4[l3];
  float4 v0 = {0,0,0,0}, v1 = {0,0,0,0}, v2 = {0,0,0,0}, v3 = {0,0,0,0};
  const float4* base = (const float4*)P0 + (size_t)(gb * 1024 + i0) * 256;

  // preload all 8 R values (off the critical chain)
  float rreg[8];
#pragma unroll
  for (int r = 0; r < 8; r++) rreg[r] = R[rbase + r];

  // prologue: load pair 0 (rows 0,1)
  float4 a0 = base[l0], a1 = base[l1], a2 = base[l2], a3 = base[l3];
  float4 b0f = base[256 + l0], b1f = base[256 + l1], b2f = base[256 + l2], b3f = base[256 + l3];

#pragma unroll
  for (int r = 0; r < 8; r += 2) {
    float4 na0, na1, na2, na3, nb0, nb1, nb2, nb3;
    if (r + 2 < 8) {                            // prefetch next pair
      const float4* nxt = base + (r + 2) * 256;
      na0 = nxt[l0]; na1 = nxt[l1]; na2 = nxt[l2]; na3 = nxt[l3];
      nb0 = nxt[256 + l0]; nb1 = nxt[256 + l1]; nb2 = nxt[256 + l2]; nb3 = nxt[256 + l3];
    }
    float ua = dot4(a3, c3, dot4(a2, c2, dot4(a1, c1, dot4(a0, c0, 0.f))));
    float ub = dot4(b3f, c3, dot4(b2f, c2, dot4(b1f, c1, dot4(b0f, c0, 0.f))));
    wave_sum2(ua, ub);
    float rva = rreg[r], rvb = rreg[r + 1];
    rva = fminf(rva / fmaf(rva, ua, EPSF), 1e37f);
    rvb = fminf(rvb / fmaf(rvb, ub, EPSF), 1e37f);
    if (lane == 0) { R[rbase + r] = rva; R[rbase + r + 1] = rvb; }
    fma4(rva, a0, v0); fma4(rva, a1, v1); fma4(rva, a2, v2); fma4(rva, a3, v3);
    fma4(rvb, b0f, v0); fma4(rvb, b1f, v1); fma4(rvb, b2f, v2); fma4(rvb, b3f, v3);
    if (r + 2 < 8) {
      a0 = na0; a1 = na1; a2 = na2; a3 = na3;
      b0f = nb0; b1f = nb1; b2f = nb2; b3f = nb3;
    }
  }
  // per-wave LDS regions (no atomics, b128 writes), then column sum across 8 waves
  float4* vb4 = (float4*)vbuf;
  vb4[wave * 256 + l0] = v0; vb4[wave * 256 + l1] = v1;
  vb4[wave * 256 + l2] = v2; vb4[wave * 256 + l3] = v3;
  __syncthreads();
  for (int col = tid; col < 1024; col += 512) {
    float v = 0.f;
#pragma unroll
    for (int w = 0; w < 8; w++) v += vbuf[w * 1024 + col];
    vcur[(size_t)(slice * G + gb) * 1024 + col] = v;
  }
}

// final C_20 = f(C_19, v_20)
__global__ __launch_bounds__(256) void cfinal_kernel(
    const float* __restrict__ Cin, float* __restrict__ Cfin,
    const float* __restrict__ vprev, int b0, int G) {
  int idx = blockIdx.x * 256 + threadIdx.x;     // < G*1024
  int gb = idx >> 10, col = idx & 1023;
  const float* vp = vprev + gb * 1024 + col;
  float v = 0.f;
#pragma unroll
  for (int s = 0; s < SINK_S; s++) v += vp[(size_t)s * G * 1024];
  int o = (b0 + gb) * 1024 + col;
  float cv = Cin[o];
  Cfin[o] = fminf(cv / fmaf(cv, v, EPSF), 1e37f);
}

// argmax over stored P0 * C + permutation gather; grid = G*128
__global__ __launch_bounds__(512) void argmaxP_kernel(
    const float* __restrict__ P0, const float* __restrict__ Cg,
    const int* __restrict__ perm, float* __restrict__ perm_out, int b0) {
  int gb = blockIdx.x >> 7, rg = blockIdx.x & 127;
  int b = b0 + gb;
  int tid = threadIdx.x;
  int wave = tid >> 6, lane = tid & 63;
  int i = rg * 8 + wave;
  const float4* Cb = (const float4*)(Cg + b * 1024);
  const float4* Prow = (const float4*)P0 + (size_t)(gb * 1024 + i) * 256;

  float best = -1.0f;
  int bj = 0;
#pragma unroll
  for (int t = 0; t < 4; t++) {
    int g = t * 64 + lane;
    float4 pv = Prow[g], cv = Cb[g];
    float val;
    val = pv.x * cv.x; if (val > best) { best = val; bj = 4 * g + 0; }
    val = pv.y * cv.y; if (val > best) { best = val; bj = 4 * g + 1; }
    val = pv.z * cv.z; if (val > best) { best = val; bj = 4 * g + 2; }
    val = pv.w * cv.w; if (val > best) { best = val; bj = 4 * g + 3; }
  }
#pragma unroll
  for (int off = 32; off > 0; off >>= 1) {
    float ob = __shfl_xor(best, off);
    int oj = __shfl_xor(bj, off);
    if (ob > best || (ob == best && oj < bj)) { best = ob; bj = oj; }
  }
  if (lane == 0) perm_out[b * 1024 + i] = (float)perm[b * 1024 + bj];
}

// ================= FALLBACK PATH (round-3, recompute) =================

__global__ __launch_bounds__(512) void sinkA_kernel(
    const float* __restrict__ Qt, const float* __restrict__ Kt,
    const float* __restrict__ E1, const float* __restrict__ E2,
    const float* __restrict__ C, float* __restrict__ R) {
  __shared__ float4 Kl[3584];
  int b = blockIdx.x >> 5, blk = blockIdx.x & 31;
  int tid = threadIdx.x;
  const float4* Ktb = (const float4*)(Kt + b * 14336);
  for (int idx = tid; idx < 3584; idx += 512) Kl[idx] = Ktb[idx];
  __syncthreads();
  int wave = tid >> 6, lane = tid & 63;
  int i0 = blk * 32 + wave * 4;
  float q[4][14], e1r[4], e2r[4], u[4];
#pragma unroll
  for (int rr = 0; rr < 4; rr++) {
#pragma unroll
    for (int d = 0; d < 14; d++) q[rr][d] = Qt[b * 14336 + d * 1024 + i0 + rr];
    e1r[rr] = E1[b * 1024 + i0 + rr];
    e2r[rr] = E2[b * 1024 + i0 + rr];
    u[rr] = 0.f;
  }
  const float4* Cb = (const float4*)(C + b * 1024);
#pragma unroll
  for (int t = 0; t < 4; t++) {
    int g = t * 64 + lane;
    float4 kv[14];
#pragma unroll
    for (int d = 0; d < 14; d++) kv[d] = Kl[d * 256 + g];
    float4 cv = Cb[g];
#pragma unroll
    for (int rr = 0; rr < 4; rr++) {
      float4 s1 = {0,0,0,0}, s2 = {0,0,0,0};
#pragma unroll
      for (int d = 0; d < 7; d++)  fma4(q[rr][d], kv[d], s1);
#pragma unroll
      for (int d = 7; d < 14; d++) fma4(q[rr][d], kv[d], s2);
      u[rr] += p0e(s1.x, s2.x, e1r[rr], e2r[rr]) * cv.x;
      u[rr] += p0e(s1.y, s2.y, e1r[rr], e2r[rr]) * cv.y;
      u[rr] += p0e(s1.z, s2.z, e1r[rr], e2r[rr]) * cv.z;
      u[rr] += p0e(s1.w, s2.w, e1r[rr], e2r[rr]) * cv.w;
    }
  }
#pragma unroll
  for (int rr = 0; rr < 4; rr++) u[rr] = wave_sum(u[rr]);
  if (lane == 0) {
#pragma unroll
    for (int rr = 0; rr < 4; rr++) {
      int o = b * 1024 + i0 + rr;
      float rv = R[o];
      R[o] = fminf(rv / fmaf(rv, u[rr], EPSF), 1e37f);
    }
  }
}

__global__ __launch_bounds__(512) void sinkB_kernel(
    const float* __restrict__ Qt, const float* __restrict__ Kt,
    const float* __restrict__ E1, const float* __restrict__ E2,
    const float* __restrict__ R, float* __restrict__ C) {
  __shared__ float4 Ql[3584];
  int b = blockIdx.x >> 5, blk = blockIdx.x & 31;
  int tid = threadIdx.x;
  const float4* Qtb = (const float4*)(Qt + b * 14336);
  for (int idx = tid; idx < 3584; idx += 512) Ql[idx] = Qtb[idx];
  __syncthreads();
  int wave = tid >> 6, lane = tid & 63;
  int j0 = blk * 32 + wave * 4;
  float kk[4][14], v[4];
#pragma unroll
  for (int rr = 0; rr < 4; rr++) {
#pragma unroll
    for (int d = 0; d < 14; d++) kk[rr][d] = Kt[b * 14336 + d * 1024 + j0 + rr];
    v[rr] = 0.f;
  }
  const float4* E1b = (const float4*)(E1 + b * 1024);
  const float4* E2b = (const float4*)(E2 + b * 1024);
  const float4* Rb  = (const float4*)(R + b * 1024);
#pragma unroll
  for (int t = 0; t < 4; t++) {
    int g = t * 64 + lane;
    float4 qv[14];
#pragma unroll
    for (int d = 0; d < 14; d++) qv[d] = Ql[d * 256 + g];
    float4 e1v = E1b[g], e2v = E2b[g], rv = Rb[g];
#pragma unroll
    for (int rr = 0; rr < 4; rr++) {
      float4 s1 = {0,0,0,0}, s2 = {0,0,0,0};
#pragma unroll
      for (int d = 0; d < 7; d++)  fma4(kk[rr][d], qv[d], s1);
#pragma unroll
      for (int d = 7; d < 14; d++) fma4(kk[rr][d], qv[d], s2);
      v[rr] += p0e(s1.x, s2.x, e1v.x, e2v.x) * rv.x;
      v[rr] += p0e(s1.y, s2.y, e1v.y, e2v.y) * rv.y;
      v[rr] += p0e(s1.z, s2.z, e1v.z, e2v.z) * rv.z;
      v[rr] += p0e(s1.w, s2.w, e1v.w, e2v.w) * rv.w;
    }
  }
#pragma unroll
  for (int rr = 0; rr < 4; rr++) v[rr] = wave_sum(v[rr]);
  if (lane == 0) {
#pragma unroll
    for (int rr = 0; rr < 4; rr++) {
      int o = b * 1024 + j0 + rr;
      float cv = C[o];
      C[o] = fminf(cv / fmaf(cv, v[rr], EPSF), 1e37f);
    }
  }
}

__global__ __launch_bounds__(512) void argmax_kernel(
    const float* __restrict__ Qt, const float* __restrict__ Kt,
    const float* __restrict__ E1, const float* __restrict__ E2,
    const float* __restrict__ C, const int* __restrict__ perm,
    float* __restrict__ perm_out) {
  __shared__ float4 Kl[3584];
  int b = blockIdx.x >> 7, rg = blockIdx.x & 127;
  int tid = threadIdx.x;
  const float4* Ktb = (const float4*)(Kt + b * 14336);
  for (int idx = tid; idx < 3584; idx += 512) Kl[idx] = Ktb[idx];
  __syncthreads();
  int wave = tid >> 6, lane = tid & 63;
  int i = rg * 8 + wave;
  int row = b * 1024 + i;
  float q[14];
#pragma unroll
  for (int d = 0; d < 14; d++) q[d] = Qt[b * 14336 + d * 1024 + i];
  float e1r = E1[row], e2r = E2[row];
  const float4* Cb = (const float4*)(C + b * 1024);
  float best = -1.0f;
  int bj = 0;
#pragma unroll
  for (int t = 0; t < 4; t++) {
    int g = t * 64 + lane;
    float4 kv[14];
#pragma unroll
    for (int d = 0; d < 14; d++) kv[d] = Kl[d * 256 + g];
    float4 cv = Cb[g];
    float4 s1 = {0,0,0,0}, s2 = {0,0,0,0};
#pragma unroll
    for (int d = 0; d < 7; d++)  fma4(q[d], kv[d], s1);
#pragma unroll
    for (int d = 7; d < 14; d++) fma4(q[d], kv[d], s2);
    float val;
    val = p0e(s1.x, s2.x, e1r, e2r) * cv.x; if (val > best) { best = val; bj = 4 * g + 0; }
    val = p0e(s1.y, s2.y, e1r, e2r) * cv.y; if (val > best) { best = val; bj = 4 * g + 1; }
    val = p0e(s1.z, s2.z, e1r, e2r) * cv.z; if (val > best) { best = val; bj = 4 * g + 2; }
    val = p0e(s1.w, s2.w, e1r, e2r) * cv.w; if (val > best) { best = val; bj = 4 * g + 3; }
  }
#pragma unroll
  for (int off = 32; off > 0; off >>= 1) {
    float ob = __shfl_xor(best, off);
    int oj = __shfl_xor(bj, off);
    if (ob > best || (ob == best && oj < bj)) { best = ob; bj = oj; }
  }
  if (lane == 0) perm_out[row] = (float)perm[b * 1024 + bj];
}

// ---------------- launch ----------------
extern "C" void kernel_launch(void* const* d_in, const int* in_sizes, int n_in,
                              void* d_out, int out_size, void* d_ws, size_t ws_size,
                              hipStream_t stream) {
  const float* x    = (const float*)d_in[0];
  const float* cert = (const float*)d_in[1];
  const int*   perm = (const int*)d_in[2];
  const float* Wq = (const float*)d_in[3];
  const float* bq = (const float*)d_in[4];
  const float* Wk = (const float*)d_in[5];
  const float* bk = (const float*)d_in[6];
  const float* Wv = (const float*)d_in[7];
  const float* bv = (const float*)d_in[8];
  const float* Wo = (const float*)d_in[9];
  const float* bo = (const float*)d_in[10];

  float* out      = (float*)d_out;            // 917504
  float* cert_out = out + 917504;             // 65536
  float* perm_out = out + 983040;             // 65536

  float* ws = (float*)d_ws;
  float* Qt = ws;                    // 917504
  float* Kt = Qt + 917504;           // 917504
  float* Vt = Kt + 917504;           // 917504
  float* E1 = Vt + 917504;           // 65536
  float* E2 = E1 + 65536;            // 65536
  float* R  = E2 + 65536;            // 65536
  float* CA = R + 65536;             // 65536  (C ping)
  float* CB = CA + 65536;            // 65536  (C pong)
  float* attn_o = CB + 65536;        // 917504  (base ends: 3,997,696 floats)
  float* vpp0   = attn_o + 917504;   // 16*G*1024 (fast path)
  // vpp1, P0 laid out after vpp0 depending on G

  // choose batch-group size G by available workspace
  // need(G) = base + 2*16*G*1024 (vpart x2) + G*1048576 (P0)
  size_t base_f = 3997696u;
  size_t avail_f = (ws_size / 4 > base_f) ? (ws_size / 4 - base_f) : 0;
  int G = 0;
  if (avail_f >= (size_t)64 * (32768 + 1048576)) G = 64;
  else if (avail_f >= (size_t)32 * (32768 + 1048576)) G = 32;
  else if (avail_f >= (size_t)16 * (32768 + 1048576)) G = 16;

  float* Cbuf[2] = {CA, CB};

  qkv_kernel<<<256, 256, 0, stream>>>(x, Wq, bq, Wk, bk, Wv, bv, Qt, Kt, Vt, R, CA, CB);
  attn_kernel<<<4096, 512, 0, stream>>>(Qt, Kt, Vt, cert, E1, E2, attn_o, cert_out);
  proj_kernel<<<3584, 256, 0, stream>>>(attn_o, Wo, bo, out);

  if (G >= 16) {
    float* vpp[2] = {vpp0, vpp0 + (size_t)16 * G * 1024};
    float* P0 = vpp0 + (size_t)32 * G * 1024;
    for (int b0 = 0; b0 < 64; b0 += G) {
      p0pre_kernel<<<G * 32, 512, 0, stream>>>(Qt, Kt, E1, E2, P0, b0);
      for (int it = 1; it <= 20; it++) {
        const float* vprev = (it == 1) ? nullptr : vpp[(it - 1) & 1];
        float* vcur = vpp[it & 1];
        const float* Cin = Cbuf[it & 1];
        float* Cout = Cbuf[(it + 1) & 1];
        sink_fused<<<G * SINK_S, 512, 0, stream>>>(P0, Cin, Cout, R, vprev, vcur, b0, G);
      }
      // C_20 = f(C_19, v_20); C_19 is in Cbuf[1], v_20 in vpp[0]; write to Cbuf[0]
      cfinal_kernel<<<G * 4, 256, 0, stream>>>(Cbuf[1], Cbuf[0], vpp[0], b0, G);
      argmaxP_kernel<<<G * 128, 512, 0, stream>>>(P0, Cbuf[0], perm, perm_out, b0);
    }
  } else {
    for (int it = 0; it < 20; it++) {
      sinkA_kernel<<<2048, 512, 0, stream>>>(Qt, Kt, E1, E2, CA, R);
      sinkB_kernel<<<2048, 512, 0, stream>>>(Qt, Kt, E1, E2, R, CA);
    }
    argmax_kernel<<<8192, 512, 0, stream>>>(Qt, Kt, E1, E2, CA, perm, perm_out);
  }
}